// Round 9
// baseline (2374.570 us; speedup 1.0000x reference)
//
#include <hip/hip_runtime.h>

#define NT 512
#define ND 256
#define NH 1024
#define NB 64
// R9 = R8 (tagged-word handoff) with asm modifier-order fix:
// "off offset:16 sc0 sc1" (offset BEFORE cache flags — gfx950 assembler req).
// hbuf u32[2][NB][NH]: word = (bf16(h)<<16) | (t+1). Consumers poll their own
// B-fragment words until every word shows tag t; on hit the fragment is already
// in registers (single LLC round-trip). No flag array, no producer drain.
// cpart/gpart double-buffered by t&1 (1-step skew bound).
// Grid 256 wgs = 4 batch-groups(16 batches) x 64 slices(16 rows); block = 4 waves.

typedef float f32x4 __attribute__((ext_vector_type(4)));
typedef short bf16x8 __attribute__((ext_vector_type(8)));

__device__ __forceinline__ unsigned short f2bf(float f) {     // RNE
  unsigned u = __builtin_bit_cast(unsigned, f);
  u += 0x7fffu + ((u >> 16) & 1u);
  return (unsigned short)(u >> 16);
}
__device__ __forceinline__ float bflo(unsigned u) {
  return __builtin_bit_cast(float, u << 16);
}
__device__ __forceinline__ float bfhi(unsigned u) {
  return __builtin_bit_cast(float, u & 0xffff0000u);
}
__device__ __forceinline__ bf16x8 pack8(float4 a, float4 b) {
  bf16x8 r;
  r[0] = (short)f2bf(a.x); r[1] = (short)f2bf(a.y);
  r[2] = (short)f2bf(a.z); r[3] = (short)f2bf(a.w);
  r[4] = (short)f2bf(b.x); r[5] = (short)f2bf(b.y);
  r[6] = (short)f2bf(b.z); r[7] = (short)f2bf(b.w);
  return r;
}

__global__ void __launch_bounds__(256, 1)
rnn_step_kernel(const float* __restrict__ x,
                const float* __restrict__ Wx_w,
                const float* __restrict__ Wx_b,
                const float* __restrict__ Wh_w,
                const float* __restrict__ Ws_w,
                const float* __restrict__ Ws_b,
                const float* __restrict__ Us_w,
                float* __restrict__ out,
                unsigned* __restrict__ hbuf)   // u32 [2][NB][NH] tagged
{
  const int tid = (int)threadIdx.x;
  const int w   = tid >> 6;        // wave
  const int l   = tid & 63;        // lane
  const int bm  = l & 15;          // mfma row/col index for A/B frags
  const int lg  = l >> 4;          // lane group
  const int sl  = (int)blockIdx.x & 63;
  const int bg  = (int)blockIdx.x >> 6;
  const int r_base = sl * 16;
  const int b_base = bg * 16;
  const int ro = tid & 15;         // epilogue: consecutive lanes -> consecutive rows
  const int bo = tid >> 4;
  const int rg = r_base + ro;
  const int b_glob = b_base + bo;

  __shared__ unsigned short us_sh[1024];      // bf16 Us
  __shared__ float cpart[2][4][4][72];        // DOUBLE-BUFFERED per-wave C partials
  __shared__ float gpart[2][4][16];           // DOUBLE-BUFFERED gate partials

  // ---- one-time: Us -> bf16 LDS ----
  {
    const float4 uv = *(const float4*)(Us_w + tid*4);
    us_sh[tid*4+0] = f2bf(uv.x); us_sh[tid*4+1] = f2bf(uv.y);
    us_sh[tid*4+2] = f2bf(uv.z); us_sh[tid*4+3] = f2bf(uv.w);
  }

  // ---- A-fragments in registers (bf16), held all 512 steps ----
  // A layout (m89): row = l&15, k = ktile + (l>>4)*8 + j
  bf16x8 whf[8];   // wave w: h-K slice [w*256, w*256+256) -> 8 mfma
  bf16x8 wxf[2];   // wave w: x-K slice [w*64, w*64+64)    -> 2 mfma
  float4 wsf[4];   // Ws f32 slice for gate-x
  {
    const int ar = r_base + bm;
    #pragma unroll
    for (int m = 0; m < 8; ++m) {
      const int k0 = w*256 + m*32 + lg*8;
      const float4 f0 = *(const float4*)(Wh_w + (size_t)ar*NH + k0);
      const float4 f1 = *(const float4*)(Wh_w + (size_t)ar*NH + k0 + 4);
      whf[m] = pack8(f0, f1);
    }
    #pragma unroll
    for (int m = 0; m < 2; ++m) {
      const int k0 = w*64 + m*32 + lg*8;
      const float4 f0 = *(const float4*)(Wx_w + (size_t)ar*ND + k0);
      const float4 f1 = *(const float4*)(Wx_w + (size_t)ar*ND + k0 + 4);
      wxf[m] = pack8(f0, f1);
      wsf[m*2]   = *(const float4*)(Ws_w + k0);
      wsf[m*2+1] = *(const float4*)(Ws_w + k0 + 4);
    }
  }
  const float wxb_r = Wx_b[rg];
  const float whd_r = Wh_w[(size_t)rg*NH + rg];
  const float usr_r = Us_w[rg];
  const float wsb   = Ws_b[0];

  float* const hs_o = out + (size_t)NB*NT;
  float* const g_o  = hs_o + (size_t)NB*NT*NH;
  float* const l_o  = g_o  + (size_t)NB*NT*NH;
  float* const rd_o = l_o  + (size_t)NB*NT*NH;

  __syncthreads();

  float myh = 0.f;

  for (int t = 0; t < NT; ++t) {
    const int p = t & 1;
    // ---- x-part: direct f32 loads, in-reg pack, 2 mfma + gate-x (f32) ----
    f32x4 acc = {0.f, 0.f, 0.f, 0.f};
    float ga = 0.f;
    {
      const float* xrow = x + ((size_t)(b_base+bm)*NT + t)*ND + w*64 + lg*8;
      #pragma unroll
      for (int m = 0; m < 2; ++m) {
        const float4 f0 = *(const float4*)(xrow + m*32);
        const float4 f1 = *(const float4*)(xrow + m*32 + 4);
        acc = __builtin_amdgcn_mfma_f32_16x16x32_bf16(
                wxf[m], pack8(f0, f1), acc, 0, 0, 0);
        ga += wsf[m*2].x*f0.x + wsf[m*2].y*f0.y + wsf[m*2].z*f0.z + wsf[m*2].w*f0.w
            + wsf[m*2+1].x*f1.x + wsf[m*2+1].y*f1.y + wsf[m*2+1].z*f1.z + wsf[m*2+1].w*f1.w;
      }
    }

    // ---- poll h_{t-1} tagged words (the poll IS the data load), h mfma ----
    if (t > 0) {
      const unsigned tag = (unsigned)t & 0xffffu;
      const unsigned* hrow =
          hbuf + ((size_t)((t-1)&1)*NB + b_base + bm)*NH + w*256 + lg*8;
      uint4 hv[16];
      while (true) {
        #pragma unroll
        for (int m = 0; m < 8; ++m)
          asm volatile("global_load_dwordx4 %0, %2, off sc0 sc1\n\t"
                       "global_load_dwordx4 %1, %2, off offset:16 sc0 sc1"
                       : "=&v"(hv[2*m]), "=&v"(hv[2*m+1])
                       : "v"(hrow + (size_t)m*32) : "memory");
        asm volatile("s_waitcnt vmcnt(0)" ::: "memory");
        bool ok = true;
        #pragma unroll
        for (int i = 0; i < 16; ++i)
          ok = ok & ((hv[i].x & 0xffffu) == tag) & ((hv[i].y & 0xffffu) == tag)
                  & ((hv[i].z & 0xffffu) == tag) & ((hv[i].w & 0xffffu) == tag);
        if (__all((int)ok)) break;
        __builtin_amdgcn_s_sleep(1);
      }
      __builtin_amdgcn_sched_barrier(0);
      #pragma unroll
      for (int m = 0; m < 8; ++m) {
        const uint4 a0 = hv[2*m], a1 = hv[2*m+1];
        uint4 bu;
        bu.x = (a0.x >> 16) | (a0.y & 0xffff0000u);
        bu.y = (a0.z >> 16) | (a0.w & 0xffff0000u);
        bu.z = (a1.x >> 16) | (a1.y & 0xffff0000u);
        bu.w = (a1.z >> 16) | (a1.w & 0xffff0000u);
        acc = __builtin_amdgcn_mfma_f32_16x16x32_bf16(
                whf[m], __builtin_bit_cast(bf16x8, bu), acc, 0, 0, 0);
        const uint4 uu = *(const uint4*)&us_sh[w*256 + m*32 + lg*8];
        ga += bflo(uu.x)*bfhi(a0.x) + bfhi(uu.x)*bfhi(a0.y)
            + bflo(uu.y)*bfhi(a0.z) + bfhi(uu.y)*bfhi(a0.w)
            + bflo(uu.z)*bfhi(a1.x) + bfhi(uu.z)*bfhi(a1.y)
            + bflo(uu.w)*bfhi(a1.z) + bfhi(uu.w)*bfhi(a1.w);
      }
    }

    // ---- combine partials (parity-indexed LDS, one barrier) ----
    ga += __shfl_xor(ga, 16, 64);
    ga += __shfl_xor(ga, 32, 64);
    if (l < 16) gpart[p][w][l] = ga;
    cpart[p][w][0][l] = acc[0];
    cpart[p][w][1][l] = acc[1];
    cpart[p][w][2][l] = acc[2];
    cpart[p][w][3][l] = acc[3];
    __syncthreads();                   // barrier (a) — the only one per step

    // ---- epilogue: 1 output per thread (row ro, batch bo) ----
    // C mapping (m89): col(lane&15)=batch, row=(lane>>4)*4+reg
    const float gsum = gpart[p][0][bo] + gpart[p][1][bo] +
                       gpart[p][2][bo] + gpart[p][3][bo];
    const int ci = ro & 3, cl = ((ro >> 2) << 4) + bo;
    const float pre0 = cpart[p][0][ci][cl] + cpart[p][1][ci][cl] +
                       cpart[p][2][ci][cl] + cpart[p][3][ci][cl];
    const float sg   = 1.f / (1.f + expf(-(gsum + wsb)));
    const float pre  = pre0 + wxb_r;
    const float htld = tanhf(pre);
    const float hp   = myh;
    const float h    = (1.f - sg)*hp + sg*htld;
    myh = h;
    {
      const unsigned word = ((unsigned)f2bf(h) << 16) | ((unsigned)(t+1) & 0xffffu);
      unsigned* hptr = hbuf + ((size_t)p*NB + b_glob)*NH + rg;
      asm volatile("global_store_dword %0, %1, off sc0 sc1"
                   :: "v"(hptr), "v"(word) : "memory");
    }

    // ---- outputs (fire-and-forget, nontemporal, full 64B lines) ----
    {
      const size_t obase = ((size_t)b_glob*NT + t)*NH + rg;
      const float sp = sg * (1.f - sg);
      __builtin_nontemporal_store(h, &hs_o[obase]);
      __builtin_nontemporal_store(sg, &g_o[obase]);
      __builtin_nontemporal_store(1.f - sg, &l_o[obase]);
      __builtin_nontemporal_store((htld - hp)*(sp*usr_r) + sg*(1.f - htld*htld)*whd_r,
                                  &rd_o[obase]);
    }
  }
}

// ys[b,t] = out_w . hs[b,t,:] + out_b
__global__ void yfinish_kernel(const float* __restrict__ hs,
                               const float* __restrict__ out_w,
                               const float* __restrict__ out_b,
                               float* __restrict__ ys)
{
  const int row  = (int)blockIdx.x*4 + ((int)threadIdx.x >> 6);
  const int lane = (int)threadIdx.x & 63;
  const float4* hp = (const float4*)(hs + (size_t)row*NH);
  const float4* wp = (const float4*)out_w;
  float s = 0.f;
  #pragma unroll
  for (int i = 0; i < 4; ++i) {
    const float4 h4 = hp[i*64 + lane];
    const float4 w4 = wp[i*64 + lane];
    s += h4.x*w4.x + h4.y*w4.y + h4.z*w4.z + h4.w*w4.w;
  }
  #pragma unroll
  for (int off = 32; off > 0; off >>= 1) s += __shfl_xor(s, off, 64);
  if (lane == 0) ys[row] = s + out_b[0];
}

extern "C" void kernel_launch(void* const* d_in, const int* in_sizes, int n_in,
                              void* d_out, int out_size, void* d_ws, size_t ws_size,
                              hipStream_t stream)
{
  (void)in_sizes; (void)n_in; (void)out_size; (void)ws_size;
  const float* x     = (const float*)d_in[0];
  const float* Wx_w  = (const float*)d_in[1];
  const float* Wx_b  = (const float*)d_in[2];
  const float* Wh_w  = (const float*)d_in[3];
  const float* Ws_w  = (const float*)d_in[4];
  const float* Ws_b  = (const float*)d_in[5];
  const float* Us_w  = (const float*)d_in[6];
  const float* out_w = (const float*)d_in[7];
  const float* out_b = (const float*)d_in[8];
  float* out = (float*)d_out;

  unsigned* hbuf = (unsigned*)d_ws;   // u32 [2][NB][NH] = 512 KB

  // zero tags each launch (kills cross-replay tag aliasing)
  hipMemsetAsync(hbuf, 0, (size_t)2*NB*NH*sizeof(unsigned), stream);
  rnn_step_kernel<<<dim3(256), dim3(256), 0, stream>>>(
      x, Wx_w, Wx_b, Wh_w, Ws_w, Ws_b, Us_w, out, hbuf);
  yfinish_kernel<<<dim3((NB*NT)/4), dim3(256), 0, stream>>>(
      out + (size_t)NB*NT, out_w, out_b, out);
}